// Round 11
// baseline (234.299 us; speedup 1.0000x reference)
//
#include <hip/hip_runtime.h>
#include <cstdint>

#define NFEAT 128
#define CHUNK 4096
#define MAXBUCK 392

typedef _Float16 half8 __attribute__((ext_vector_type(8)));
typedef float f32x4 __attribute__((ext_vector_type(4)));

// ---------------- prep: zero bucket counters + both weight transposes ----------------

__global__ void prep_k(int* __restrict__ gcount, int nbuck,
                       const float* __restrict__ W1, const float* __restrict__ W2,
                       _Float16* __restrict__ WT1, _Float16* __restrict__ WT2) {
    int i = blockIdx.x * blockDim.x + threadIdx.x;
    if (i < nbuck) gcount[i] = 0;
    if (i < 16384) {
        int n = i >> 7, k = i & 127;
        WT1[i] = (_Float16)W1[k * NFEAT + n];
        WT2[i] = (_Float16)W2[k * NFEAT + n];
    }
}

// ---------------- bucket histogram ----------------

__global__ __launch_bounds__(256) void bhist_k(const int* __restrict__ dst, int E,
                                               int* __restrict__ gcount, int nbuck) {
    __shared__ int lh[MAXBUCK];
    int e0 = blockIdx.x * CHUNK;
    int e1 = min(e0 + CHUNK, E);
    for (int i = threadIdx.x; i < nbuck; i += 256) lh[i] = 0;
    __syncthreads();
    for (int e = e0 + threadIdx.x; e < e1; e += 256)
        atomicAdd(&lh[dst[e] >> 8], 1);
    __syncthreads();
    for (int b = threadIdx.x; b < nbuck; b += 256)
        if (lh[b] > 0) atomicAdd(&gcount[b], lh[b]);
}

// ---------------- bucket scan ----------------

__global__ void bscan_k(const int* __restrict__ gcount, int* __restrict__ bucket_base,
                        int* __restrict__ bfill, int nbuck) {
    __shared__ int s[512];
    int t = threadIdx.x;
    int v = (t < nbuck) ? gcount[t] : 0;
    s[t] = v;
    __syncthreads();
    for (int off = 1; off < 512; off <<= 1) {
        int tv = (t >= off) ? s[t - off] : 0;
        __syncthreads();
        s[t] += tv;
        __syncthreads();
    }
    if (t < nbuck) {
        bucket_base[t] = s[t] - v;  // exclusive
        bfill[t] = 0;
    }
}

// ---------------- binA2: block-staged radix append ----------------

__global__ __launch_bounds__(256) void binA2_k(const int* __restrict__ src,
                                               const int* __restrict__ dst,
                                               const int* __restrict__ bucket_base,
                                               int* __restrict__ bfill,
                                               unsigned* __restrict__ binned,
                                               int E, int nbuck) {
    __shared__ int lhist[MAXBUCK];
    __shared__ int lbase[MAXBUCK];
    int e0 = blockIdx.x * CHUNK;
    int e1 = min(e0 + CHUNK, E);
    for (int i = threadIdx.x; i < nbuck; i += 256) lhist[i] = 0;
    __syncthreads();
    for (int e = e0 + threadIdx.x; e < e1; e += 256)
        atomicAdd(&lhist[dst[e] >> 8], 1);
    __syncthreads();
    for (int b = threadIdx.x; b < nbuck; b += 256) {
        int c = lhist[b];
        if (c > 0) lbase[b] = bucket_base[b] + atomicAdd(&bfill[b], c);
        lhist[b] = 0;
    }
    __syncthreads();
    for (int e = e0 + threadIdx.x; e < e1; e += 256) {
        int d = dst[e], s = src[e];
        int b = d >> 8;
        int r = atomicAdd(&lhist[b], 1);
        binned[lbase[b] + r] = ((unsigned)s << 8) | (unsigned)(d & 255);
    }
}

// ---------------- binB2: per-bucket counting sort; emits rowptr + dinv ----------

__global__ __launch_bounds__(256) void binB2_k(const unsigned* __restrict__ binned,
                                               const int* __restrict__ bucket_base,
                                               int* __restrict__ rowptr,
                                               float* __restrict__ dinv,
                                               int* __restrict__ csr_src,
                                               int N, int E, int nbuck) {
    __shared__ int cnt[256];
    __shared__ int sc[256];
    __shared__ int ex[256];
    __shared__ int fill[256];
    __shared__ int stage[8192];
    int b = blockIdx.x;
    int t = threadIdx.x;
    int n0 = b << 8;
    int nn = min(256, N - n0);
    int base = bucket_base[b];
    int bcnt = ((b + 1 < nbuck) ? bucket_base[b + 1] : E) - base;

    cnt[t] = 0;
    fill[t] = 0;
    __syncthreads();
    for (int i = t; i < bcnt; i += 256)
        atomicAdd(&cnt[binned[base + i] & 255u], 1);
    __syncthreads();
    int v = cnt[t];
    sc[t] = v;
    __syncthreads();
    for (int off = 1; off < 256; off <<= 1) {
        int tv = (t >= off) ? sc[t - off] : 0;
        __syncthreads();
        sc[t] += tv;
        __syncthreads();
    }
    ex[t] = sc[t] - v;
    if (t < nn) {
        rowptr[n0 + t] = base + ex[t];
        dinv[n0 + t] = rsqrtf((float)(1 + v));
    }
    if (b == nbuck - 1 && t == 0) rowptr[N] = E;
    __syncthreads();
    for (int i = t; i < bcnt; i += 256) {
        unsigned p = binned[base + i];
        int dl = (int)(p & 255u);
        int s = (int)(p >> 8);
        int pos = ex[dl] + atomicAdd(&fill[dl], 1);
        if (pos < 8192) stage[pos] = s;
        else csr_src[base + pos] = s;
    }
    __syncthreads();
    int m = bcnt < 8192 ? bcnt : 8192;
    for (int i = t; i < m; i += 256) csr_src[base + i] = stage[i];
}

// ---------------- MFMA f16 GEMM: H = (X @ W) * dinv[row]  (f16 row-major out) ----
// A-fragments loaded global->reg directly (MFMA layout, 64B-line granular);
// only B (WT, 32KB swizzled) goes through LDS -> 32KB LDS, no A staging barrier.

template <bool SRC_F16>
__global__ __launch_bounds__(256) void gemm_mfma_k(const void* __restrict__ Xv,
                                                   const _Float16* __restrict__ WT,
                                                   const float* __restrict__ dinvp,
                                                   _Float16* __restrict__ H, int nrows) {
    __shared__ char ldsB[32768];
    const int t = threadIdx.x;
    const int row0 = blockIdx.x * 128;
    const int w = t >> 6, lane = t & 63;
    const int wr = w >> 1, wc = w & 1;
    const int lrow = lane & 15, kgrp = lane >> 4;

    // stage B: 8 rounds x 256 threads x 16B, XOR-swizzled
#pragma unroll
    for (int i = 0; i < 8; ++i) {
        int chunk = i * 256 + t;
        int r = chunk >> 4, cb = chunk & 15;
        half8 hv = *(const half8*)(WT + (size_t)r * NFEAT + cb * 8);
        int byte = (r * 256 + cb * 16) ^ ((r & 7) << 4);
        *(half8*)(ldsB + byte) = hv;
    }

    f32x4 acc[4][4];
#pragma unroll
    for (int m = 0; m < 4; ++m)
#pragma unroll
        for (int n = 0; n < 4; ++n) acc[m][n] = (f32x4)0.f;

    // A fragment rows for this lane
    int arow[4];
    bool aok[4];
#pragma unroll
    for (int m = 0; m < 4; ++m) {
        arow[m] = row0 + wr * 64 + m * 16 + lrow;
        aok[m] = arow[m] < nrows;
    }

    if (SRC_F16) {
        // preload all 16 A fragments (64 VGPR) before the barrier
        const _Float16* X = (const _Float16*)Xv;
        half8 a[4][4];
#pragma unroll
        for (int kk = 0; kk < 4; ++kk)
#pragma unroll
            for (int m = 0; m < 4; ++m)
                a[kk][m] = aok[m]
                    ? *(const half8*)(X + (size_t)arow[m] * NFEAT + kk * 32 + kgrp * 8)
                    : (half8)(_Float16)0.f;
        __syncthreads();
#pragma unroll
        for (int kk = 0; kk < 4; ++kk) {
            int kb = (kk * 32 + kgrp * 8) * 2;
            half8 b[4];
#pragma unroll
            for (int n = 0; n < 4; ++n) {
                int c = wc * 64 + n * 16 + lrow;
                b[n] = *(const half8*)(ldsB + ((c * 256 + kb) ^ ((c & 7) << 4)));
            }
#pragma unroll
            for (int m = 0; m < 4; ++m)
#pragma unroll
                for (int n = 0; n < 4; ++n)
                    acc[m][n] = __builtin_amdgcn_mfma_f32_16x16x32_f16(a[kk][m], b[n], acc[m][n], 0, 0, 0);
        }
    } else {
        const float* X = (const float*)Xv;
        __syncthreads();
#pragma unroll
        for (int kk = 0; kk < 4; ++kk) {
            half8 a[4];
#pragma unroll
            for (int m = 0; m < 4; ++m) {
                if (aok[m]) {
                    const float* p = X + (size_t)arow[m] * NFEAT + kk * 32 + kgrp * 8;
                    float4 v0 = *(const float4*)p;
                    float4 v1 = *(const float4*)(p + 4);
                    half8 hv;
                    hv[0] = (_Float16)v0.x; hv[1] = (_Float16)v0.y;
                    hv[2] = (_Float16)v0.z; hv[3] = (_Float16)v0.w;
                    hv[4] = (_Float16)v1.x; hv[5] = (_Float16)v1.y;
                    hv[6] = (_Float16)v1.z; hv[7] = (_Float16)v1.w;
                    a[m] = hv;
                } else {
                    a[m] = (half8)(_Float16)0.f;
                }
            }
            int kb = (kk * 32 + kgrp * 8) * 2;
            half8 b[4];
#pragma unroll
            for (int n = 0; n < 4; ++n) {
                int c = wc * 64 + n * 16 + lrow;
                b[n] = *(const half8*)(ldsB + ((c * 256 + kb) ^ ((c & 7) << 4)));
            }
#pragma unroll
            for (int m = 0; m < 4; ++m)
#pragma unroll
                for (int n = 0; n < 4; ++n)
                    acc[m][n] = __builtin_amdgcn_mfma_f32_16x16x32_f16(a[m], b[n], acc[m][n], 0, 0, 0);
        }
    }

    // epilogue: C/D layout col=lane&15, row=(lane>>4)*4+reg; scale by dinv[row]
#pragma unroll
    for (int m = 0; m < 4; ++m) {
#pragma unroll
        for (int j = 0; j < 4; ++j) {
            int row = row0 + wr * 64 + m * 16 + kgrp * 4 + j;
            if (row < nrows) {
                float sc = dinvp[row];
#pragma unroll
                for (int n = 0; n < 4; ++n)
                    H[(size_t)row * NFEAT + wc * 64 + n * 16 + lrow] =
                        (_Float16)(acc[m][n][j] * sc);
            }
        }
    }
}

// ---------------- CSR aggregation: one wave per node, 4 groups x 16 lanes ----

template <bool FINAL>
__global__ __launch_bounds__(256) void agg_csr_k(const int* __restrict__ rowptr,
                                                 const int* __restrict__ csr_src,
                                                 const float* __restrict__ dinv,
                                                 const _Float16* __restrict__ h,
                                                 const float* __restrict__ bias,
                                                 void* __restrict__ outv, int N) {
    int node = (int)((blockIdx.x * (unsigned)blockDim.x + threadIdx.x) >> 6);
    if (node >= N) return;
    int lane = threadIdx.x & 63;
    int g = lane >> 4;        // edge group 0..3
    int fl = lane & 15;       // feature block: feats fl*8 .. fl*8+7
    const _Float16* hfb = h + fl * 8;

    int p0 = rowptr[node], p1 = rowptr[node + 1];
    half8 ha0 = (half8)(_Float16)0.f, ha1 = ha0, ha2 = ha0, ha3 = ha0;

    int p = p0;
    for (; p + 16 <= p1; p += 16) {
        int s0 = csr_src[p + g];
        int s1 = csr_src[p + 4 + g];
        int s2 = csr_src[p + 8 + g];
        int s3 = csr_src[p + 12 + g];
        half8 v0 = *(const half8*)(hfb + (size_t)s0 * NFEAT);
        half8 v1 = *(const half8*)(hfb + (size_t)s1 * NFEAT);
        half8 v2 = *(const half8*)(hfb + (size_t)s2 * NFEAT);
        half8 v3 = *(const half8*)(hfb + (size_t)s3 * NFEAT);
        ha0 += v0; ha1 += v1; ha2 += v2; ha3 += v3;
    }
    if (p + 8 <= p1) {
        int s0 = csr_src[p + g];
        int s1 = csr_src[p + 4 + g];
        half8 v0 = *(const half8*)(hfb + (size_t)s0 * NFEAT);
        half8 v1 = *(const half8*)(hfb + (size_t)s1 * NFEAT);
        ha0 += v0; ha1 += v1;
        p += 8;
    }
    if (p + 4 <= p1) {
        int s0 = csr_src[p + g];
        half8 v0 = *(const half8*)(hfb + (size_t)s0 * NFEAT);
        ha2 += v0;
        p += 4;
    }
    if (p + g < p1) {
        int s0 = csr_src[p + g];
        half8 v0 = *(const half8*)(hfb + (size_t)s0 * NFEAT);
        ha3 += v0;
    }
    if (g == 0) {  // self-loop once
        half8 vs = *(const half8*)(hfb + (size_t)node * NFEAT);
        ha0 += vs;
    }
    ha0 += ha1;
    ha2 += ha3;
    ha0 += ha2;

    float acc[8];
#pragma unroll
    for (int i = 0; i < 8; ++i) acc[i] = (float)ha0[i];
#pragma unroll
    for (int i = 0; i < 8; ++i) {
        acc[i] += __shfl_xor(acc[i], 16, 64);
        acc[i] += __shfl_xor(acc[i], 32, 64);
    }
    if (g == 0) {
        float dd = dinv[node];
        float4 bv0 = *(const float4*)(bias + fl * 8);
        float4 bv1 = *(const float4*)(bias + fl * 8 + 4);
        float o[8];
        o[0] = fmaf(dd, acc[0], bv0.x); o[1] = fmaf(dd, acc[1], bv0.y);
        o[2] = fmaf(dd, acc[2], bv0.z); o[3] = fmaf(dd, acc[3], bv0.w);
        o[4] = fmaf(dd, acc[4], bv1.x); o[5] = fmaf(dd, acc[5], bv1.y);
        o[6] = fmaf(dd, acc[6], bv1.z); o[7] = fmaf(dd, acc[7], bv1.w);
        if (FINAL) {
            float* out = (float*)outv + (size_t)node * NFEAT + fl * 8;
            *(float4*)out = make_float4(o[0], o[1], o[2], o[3]);
            *(float4*)(out + 4) = make_float4(o[4], o[5], o[6], o[7]);
        } else {
            half8 ho;
#pragma unroll
            for (int i = 0; i < 8; ++i) ho[i] = (_Float16)fmaxf(o[i], 0.f);
            *(half8*)((_Float16*)outv + (size_t)node * NFEAT + fl * 8) = ho;
        }
    }
}

// ---------------- launch ----------------

extern "C" void kernel_launch(void* const* d_in, const int* in_sizes, int n_in,
                              void* d_out, int out_size, void* d_ws, size_t ws_size,
                              hipStream_t stream) {
    const float* x  = (const float*)d_in[0];
    const int*   ei = (const int*)d_in[1];
    const float* W1 = (const float*)d_in[2];
    const float* b1 = (const float*)d_in[3];
    const float* W2 = (const float*)d_in[4];
    const float* b2 = (const float*)d_in[5];
    float* out = (float*)d_out;

    const int N = in_sizes[0] / NFEAT;
    const int E = in_sizes[1] / 2;
    const int* srcv = ei;
    const int* dstv = ei + E;

    char* wsp = (char*)d_ws;
    size_t off = 0;
    auto alloc = [&](size_t bytes) {
        char* p = wsp + off;
        off = (off + bytes + 255) & ~(size_t)255;
        return p;
    };
    float*    dinv     = (float*)alloc((size_t)N * 4);
    int*      rowptr   = (int*)alloc((size_t)(N + 1) * 4);
    int*      gcount   = (int*)alloc(MAXBUCK * 4);
    int*      bbase    = (int*)alloc(MAXBUCK * 4);
    int*      bfill    = (int*)alloc(MAXBUCK * 4);
    int*      csr_src  = (int*)alloc((size_t)E * 4);
    _Float16* wt1      = (_Float16*)alloc(NFEAT * NFEAT * 2);
    _Float16* wt2      = (_Float16*)alloc(NFEAT * NFEAT * 2);
    _Float16* hbuf     = (_Float16*)alloc((size_t)N * NFEAT * 2);
    _Float16* a1buf    = (_Float16*)alloc((size_t)N * NFEAT * 2);
    unsigned* binned   = (unsigned*)hbuf;  // alias: consumed by binB2 before gemm1

    const int nbuck = (N + 255) >> 8;          // 391
    const int nchunk = (E + CHUNK - 1) / CHUNK;

    // build: prep -> bucket hist -> bucket scan -> binA2 -> binB2 (rowptr+dinv+sort)
    prep_k<<<64, 256, 0, stream>>>(gcount, nbuck, W1, W2, wt1, wt2);
    bhist_k<<<nchunk, 256, 0, stream>>>(dstv, E, gcount, nbuck);
    bscan_k<<<1, 512, 0, stream>>>(gcount, bbase, bfill, nbuck);
    binA2_k<<<nchunk, 256, 0, stream>>>(srcv, dstv, bbase, bfill, binned, E, nbuck);
    binB2_k<<<nbuck, 256, 0, stream>>>(binned, bbase, rowptr, dinv, csr_src, N, E, nbuck);

    const int gemm_blocks = (N + 127) / 128;
    const int agg_blocks = (int)(((size_t)N * 64 + 255) / 256);

    // layer 1: h1' = (x@W1)*dinv ; a1 = relu(dinv*Agg(h1') + b1) (f16)
    gemm_mfma_k<false><<<gemm_blocks, 256, 0, stream>>>(x, wt1, dinv, hbuf, N);
    agg_csr_k<false><<<agg_blocks, 256, 0, stream>>>(rowptr, csr_src, dinv, hbuf, b1, a1buf, N);

    // layer 2: h2' = (a1@W2)*dinv ; out = dinv*Agg(h2') + b2 (fp32)
    gemm_mfma_k<true><<<gemm_blocks, 256, 0, stream>>>(a1buf, wt2, dinv, hbuf, N);
    agg_csr_k<true><<<agg_blocks, 256, 0, stream>>>(rowptr, csr_src, dinv, hbuf, b2, out, N);
}

// Round 12
// 226.851 us; speedup vs baseline: 1.0328x; 1.0328x over previous
//
#include <hip/hip_runtime.h>
#include <cstdint>

#define NFEAT 128
#define CHUNK 4096
#define MAXBUCK 392

typedef _Float16 half8 __attribute__((ext_vector_type(8)));
typedef float f32x4 __attribute__((ext_vector_type(4)));

// ---------------- prep: zero bucket counters + both weight transposes ----------------

__global__ void prep_k(int* __restrict__ gcount, int nbuck,
                       const float* __restrict__ W1, const float* __restrict__ W2,
                       _Float16* __restrict__ WT1, _Float16* __restrict__ WT2) {
    int i = blockIdx.x * blockDim.x + threadIdx.x;
    if (i < nbuck) gcount[i] = 0;
    if (i < 16384) {
        int n = i >> 7, k = i & 127;
        WT1[i] = (_Float16)W1[k * NFEAT + n];
        WT2[i] = (_Float16)W2[k * NFEAT + n];
    }
}

// ---------------- bucket histogram ----------------

__global__ __launch_bounds__(256) void bhist_k(const int* __restrict__ dst, int E,
                                               int* __restrict__ gcount, int nbuck) {
    __shared__ int lh[MAXBUCK];
    int e0 = blockIdx.x * CHUNK;
    int e1 = min(e0 + CHUNK, E);
    for (int i = threadIdx.x; i < nbuck; i += 256) lh[i] = 0;
    __syncthreads();
    for (int e = e0 + threadIdx.x; e < e1; e += 256)
        atomicAdd(&lh[dst[e] >> 8], 1);
    __syncthreads();
    for (int b = threadIdx.x; b < nbuck; b += 256)
        if (lh[b] > 0) atomicAdd(&gcount[b], lh[b]);
}

// ---------------- bucket scan ----------------

__global__ void bscan_k(const int* __restrict__ gcount, int* __restrict__ bucket_base,
                        int* __restrict__ bfill, int nbuck) {
    __shared__ int s[512];
    int t = threadIdx.x;
    int v = (t < nbuck) ? gcount[t] : 0;
    s[t] = v;
    __syncthreads();
    for (int off = 1; off < 512; off <<= 1) {
        int tv = (t >= off) ? s[t - off] : 0;
        __syncthreads();
        s[t] += tv;
        __syncthreads();
    }
    if (t < nbuck) {
        bucket_base[t] = s[t] - v;  // exclusive
        bfill[t] = 0;
    }
}

// ---------------- binA2: block-staged radix append ----------------

__global__ __launch_bounds__(256) void binA2_k(const int* __restrict__ src,
                                               const int* __restrict__ dst,
                                               const int* __restrict__ bucket_base,
                                               int* __restrict__ bfill,
                                               unsigned* __restrict__ binned,
                                               int E, int nbuck) {
    __shared__ int lhist[MAXBUCK];
    __shared__ int lbase[MAXBUCK];
    int e0 = blockIdx.x * CHUNK;
    int e1 = min(e0 + CHUNK, E);
    for (int i = threadIdx.x; i < nbuck; i += 256) lhist[i] = 0;
    __syncthreads();
    for (int e = e0 + threadIdx.x; e < e1; e += 256)
        atomicAdd(&lhist[dst[e] >> 8], 1);
    __syncthreads();
    for (int b = threadIdx.x; b < nbuck; b += 256) {
        int c = lhist[b];
        if (c > 0) lbase[b] = bucket_base[b] + atomicAdd(&bfill[b], c);
        lhist[b] = 0;
    }
    __syncthreads();
    for (int e = e0 + threadIdx.x; e < e1; e += 256) {
        int d = dst[e], s = src[e];
        int b = d >> 8;
        int r = atomicAdd(&lhist[b], 1);
        binned[lbase[b] + r] = ((unsigned)s << 8) | (unsigned)(d & 255);
    }
}

// ---------------- binB2: per-bucket counting sort; emits rowptr + dinv ----------

__global__ __launch_bounds__(256) void binB2_k(const unsigned* __restrict__ binned,
                                               const int* __restrict__ bucket_base,
                                               int* __restrict__ rowptr,
                                               float* __restrict__ dinv,
                                               int* __restrict__ csr_src,
                                               int N, int E, int nbuck) {
    __shared__ int cnt[256];
    __shared__ int sc[256];
    __shared__ int ex[256];
    __shared__ int fill[256];
    __shared__ int stage[8192];
    int b = blockIdx.x;
    int t = threadIdx.x;
    int n0 = b << 8;
    int nn = min(256, N - n0);
    int base = bucket_base[b];
    int bcnt = ((b + 1 < nbuck) ? bucket_base[b + 1] : E) - base;

    cnt[t] = 0;
    fill[t] = 0;
    __syncthreads();
    for (int i = t; i < bcnt; i += 256)
        atomicAdd(&cnt[binned[base + i] & 255u], 1);
    __syncthreads();
    int v = cnt[t];
    sc[t] = v;
    __syncthreads();
    for (int off = 1; off < 256; off <<= 1) {
        int tv = (t >= off) ? sc[t - off] : 0;
        __syncthreads();
        sc[t] += tv;
        __syncthreads();
    }
    ex[t] = sc[t] - v;
    if (t < nn) {
        rowptr[n0 + t] = base + ex[t];
        dinv[n0 + t] = rsqrtf((float)(1 + v));
    }
    if (b == nbuck - 1 && t == 0) rowptr[N] = E;
    __syncthreads();
    for (int i = t; i < bcnt; i += 256) {
        unsigned p = binned[base + i];
        int dl = (int)(p & 255u);
        int s = (int)(p >> 8);
        int pos = ex[dl] + atomicAdd(&fill[dl], 1);
        if (pos < 8192) stage[pos] = s;
        else csr_src[base + pos] = s;
    }
    __syncthreads();
    int m = bcnt < 8192 ? bcnt : 8192;
    for (int i = t; i < m; i += 256) csr_src[base + i] = stage[i];
}

// ---------------- MFMA f16 GEMM: H = (X @ W) * dinv[row]  (f16 row-major out) ----
// R10 form: both A and B staged through LDS (coalesced + XOR-swizzled), 64KB LDS.

template <bool SRC_F16>
__global__ __launch_bounds__(256) void gemm_mfma_k(const void* __restrict__ Xv,
                                                   const _Float16* __restrict__ WT,
                                                   const float* __restrict__ dinvp,
                                                   _Float16* __restrict__ H, int nrows) {
    __shared__ uint4 ldsbuf[4096];  // 64 KB
    char* ldsA = (char*)ldsbuf;
    char* ldsB = (char*)ldsbuf + 32768;
    const int t = threadIdx.x;
    const int row0 = blockIdx.x * 128;

#pragma unroll
    for (int i = 0; i < 8; ++i) {
        int chunk = i * 256 + t;
        int r = chunk >> 4, cb = chunk & 15;
        half8 hv;
        if (row0 + r < nrows) {
            if (SRC_F16) {
                hv = *(const half8*)((const _Float16*)Xv + (size_t)(row0 + r) * NFEAT + cb * 8);
            } else {
                const float* X = (const float*)Xv;
                float4 v0 = *(const float4*)(X + (size_t)(row0 + r) * NFEAT + cb * 8);
                float4 v1 = *(const float4*)(X + (size_t)(row0 + r) * NFEAT + cb * 8 + 4);
                hv[0] = (_Float16)v0.x; hv[1] = (_Float16)v0.y;
                hv[2] = (_Float16)v0.z; hv[3] = (_Float16)v0.w;
                hv[4] = (_Float16)v1.x; hv[5] = (_Float16)v1.y;
                hv[6] = (_Float16)v1.z; hv[7] = (_Float16)v1.w;
            }
        } else {
            hv = (half8)(_Float16)0.f;
        }
        int byte = (r * 256 + cb * 16) ^ ((r & 7) << 4);
        *(half8*)(ldsA + byte) = hv;
    }
#pragma unroll
    for (int i = 0; i < 8; ++i) {
        int chunk = i * 256 + t;
        int r = chunk >> 4, cb = chunk & 15;
        half8 hv = *(const half8*)(WT + (size_t)r * NFEAT + cb * 8);
        int byte = (r * 256 + cb * 16) ^ ((r & 7) << 4);
        *(half8*)(ldsB + byte) = hv;
    }
    __syncthreads();

    const int w = t >> 6, lane = t & 63;
    const int wr = w >> 1, wc = w & 1;
    const int lrow = lane & 15, kgrp = lane >> 4;

    f32x4 acc[4][4];
#pragma unroll
    for (int m = 0; m < 4; ++m)
#pragma unroll
        for (int n = 0; n < 4; ++n) acc[m][n] = (f32x4)0.f;

#pragma unroll
    for (int kk = 0; kk < 4; ++kk) {
        int kb = (kk * 32 + kgrp * 8) * 2;
        half8 a[4], b[4];
#pragma unroll
        for (int m = 0; m < 4; ++m) {
            int r = wr * 64 + m * 16 + lrow;
            a[m] = *(const half8*)(ldsA + ((r * 256 + kb) ^ ((r & 7) << 4)));
        }
#pragma unroll
        for (int n = 0; n < 4; ++n) {
            int c = wc * 64 + n * 16 + lrow;
            b[n] = *(const half8*)(ldsB + ((c * 256 + kb) ^ ((c & 7) << 4)));
        }
#pragma unroll
        for (int m = 0; m < 4; ++m)
#pragma unroll
            for (int n = 0; n < 4; ++n)
                acc[m][n] = __builtin_amdgcn_mfma_f32_16x16x32_f16(a[m], b[n], acc[m][n], 0, 0, 0);
    }

#pragma unroll
    for (int m = 0; m < 4; ++m) {
#pragma unroll
        for (int j = 0; j < 4; ++j) {
            int row = row0 + wr * 64 + m * 16 + kgrp * 4 + j;
            if (row < nrows) {
                float sc = dinvp[row];
#pragma unroll
                for (int n = 0; n < 4; ++n)
                    H[(size_t)row * NFEAT + wc * 64 + n * 16 + lrow] =
                        (_Float16)(acc[m][n][j] * sc);
            }
        }
    }
}

// ---------------- CSR aggregation: one wave per node, 4 groups x 16 lanes ----
// 16-edge unroll: 4 half8 gathers (16B) in flight; packed f16 partials.

template <bool FINAL>
__global__ __launch_bounds__(256) void agg_csr_k(const int* __restrict__ rowptr,
                                                 const int* __restrict__ csr_src,
                                                 const float* __restrict__ dinv,
                                                 const _Float16* __restrict__ h,
                                                 const float* __restrict__ bias,
                                                 void* __restrict__ outv, int N) {
    int node = (int)((blockIdx.x * (unsigned)blockDim.x + threadIdx.x) >> 6);
    if (node >= N) return;
    int lane = threadIdx.x & 63;
    int g = lane >> 4;        // edge group 0..3
    int fl = lane & 15;       // feature block: feats fl*8 .. fl*8+7
    const _Float16* hfb = h + fl * 8;

    int p0 = rowptr[node], p1 = rowptr[node + 1];
    half8 ha0 = (half8)(_Float16)0.f, ha1 = ha0, ha2 = ha0, ha3 = ha0;

    int p = p0;
    for (; p + 16 <= p1; p += 16) {
        int s0 = csr_src[p + g];
        int s1 = csr_src[p + 4 + g];
        int s2 = csr_src[p + 8 + g];
        int s3 = csr_src[p + 12 + g];
        half8 v0 = *(const half8*)(hfb + (size_t)s0 * NFEAT);
        half8 v1 = *(const half8*)(hfb + (size_t)s1 * NFEAT);
        half8 v2 = *(const half8*)(hfb + (size_t)s2 * NFEAT);
        half8 v3 = *(const half8*)(hfb + (size_t)s3 * NFEAT);
        ha0 += v0; ha1 += v1; ha2 += v2; ha3 += v3;
    }
    if (p + 8 <= p1) {
        int s0 = csr_src[p + g];
        int s1 = csr_src[p + 4 + g];
        half8 v0 = *(const half8*)(hfb + (size_t)s0 * NFEAT);
        half8 v1 = *(const half8*)(hfb + (size_t)s1 * NFEAT);
        ha0 += v0; ha1 += v1;
        p += 8;
    }
    if (p + 4 <= p1) {
        int s0 = csr_src[p + g];
        half8 v0 = *(const half8*)(hfb + (size_t)s0 * NFEAT);
        ha2 += v0;
        p += 4;
    }
    if (p + g < p1) {
        int s0 = csr_src[p + g];
        half8 v0 = *(const half8*)(hfb + (size_t)s0 * NFEAT);
        ha3 += v0;
    }
    if (g == 0) {  // self-loop once
        half8 vs = *(const half8*)(hfb + (size_t)node * NFEAT);
        ha0 += vs;
    }
    ha0 += ha1;
    ha2 += ha3;
    ha0 += ha2;

    float acc[8];
#pragma unroll
    for (int i = 0; i < 8; ++i) acc[i] = (float)ha0[i];
#pragma unroll
    for (int i = 0; i < 8; ++i) {
        acc[i] += __shfl_xor(acc[i], 16, 64);
        acc[i] += __shfl_xor(acc[i], 32, 64);
    }
    if (g == 0) {
        float dd = dinv[node];
        float4 bv0 = *(const float4*)(bias + fl * 8);
        float4 bv1 = *(const float4*)(bias + fl * 8 + 4);
        float o[8];
        o[0] = fmaf(dd, acc[0], bv0.x); o[1] = fmaf(dd, acc[1], bv0.y);
        o[2] = fmaf(dd, acc[2], bv0.z); o[3] = fmaf(dd, acc[3], bv0.w);
        o[4] = fmaf(dd, acc[4], bv1.x); o[5] = fmaf(dd, acc[5], bv1.y);
        o[6] = fmaf(dd, acc[6], bv1.z); o[7] = fmaf(dd, acc[7], bv1.w);
        if (FINAL) {
            float* out = (float*)outv + (size_t)node * NFEAT + fl * 8;
            *(float4*)out = make_float4(o[0], o[1], o[2], o[3]);
            *(float4*)(out + 4) = make_float4(o[4], o[5], o[6], o[7]);
        } else {
            half8 ho;
#pragma unroll
            for (int i = 0; i < 8; ++i) ho[i] = (_Float16)fmaxf(o[i], 0.f);
            *(half8*)((_Float16*)outv + (size_t)node * NFEAT + fl * 8) = ho;
        }
    }
}

// ---------------- launch ----------------

extern "C" void kernel_launch(void* const* d_in, const int* in_sizes, int n_in,
                              void* d_out, int out_size, void* d_ws, size_t ws_size,
                              hipStream_t stream) {
    const float* x  = (const float*)d_in[0];
    const int*   ei = (const int*)d_in[1];
    const float* W1 = (const float*)d_in[2];
    const float* b1 = (const float*)d_in[3];
    const float* W2 = (const float*)d_in[4];
    const float* b2 = (const float*)d_in[5];
    float* out = (float*)d_out;

    const int N = in_sizes[0] / NFEAT;
    const int E = in_sizes[1] / 2;
    const int* srcv = ei;
    const int* dstv = ei + E;

    char* wsp = (char*)d_ws;
    size_t off = 0;
    auto alloc = [&](size_t bytes) {
        char* p = wsp + off;
        off = (off + bytes + 255) & ~(size_t)255;
        return p;
    };
    float*    dinv     = (float*)alloc((size_t)N * 4);
    int*      rowptr   = (int*)alloc((size_t)(N + 1) * 4);
    int*      gcount   = (int*)alloc(MAXBUCK * 4);
    int*      bbase    = (int*)alloc(MAXBUCK * 4);
    int*      bfill    = (int*)alloc(MAXBUCK * 4);
    int*      csr_src  = (int*)alloc((size_t)E * 4);
    _Float16* wt1      = (_Float16*)alloc(NFEAT * NFEAT * 2);
    _Float16* wt2      = (_Float16*)alloc(NFEAT * NFEAT * 2);
    _Float16* hbuf     = (_Float16*)alloc((size_t)N * NFEAT * 2);
    _Float16* a1buf    = (_Float16*)alloc((size_t)N * NFEAT * 2);
    unsigned* binned   = (unsigned*)hbuf;  // alias: consumed by binB2 before gemm1

    const int nbuck = (N + 255) >> 8;          // 391
    const int nchunk = (E + CHUNK - 1) / CHUNK;

    // build: prep -> bucket hist -> bucket scan -> binA2 -> binB2 (rowptr+dinv+sort)
    prep_k<<<64, 256, 0, stream>>>(gcount, nbuck, W1, W2, wt1, wt2);
    bhist_k<<<nchunk, 256, 0, stream>>>(dstv, E, gcount, nbuck);
    bscan_k<<<1, 512, 0, stream>>>(gcount, bbase, bfill, nbuck);
    binA2_k<<<nchunk, 256, 0, stream>>>(srcv, dstv, bbase, bfill, binned, E, nbuck);
    binB2_k<<<nbuck, 256, 0, stream>>>(binned, bbase, rowptr, dinv, csr_src, N, E, nbuck);

    const int gemm_blocks = (N + 127) / 128;
    const int agg_blocks = (int)(((size_t)N * 64 + 255) / 256);

    // layer 1: h1' = (x@W1)*dinv ; a1 = relu(dinv*Agg(h1') + b1) (f16)
    gemm_mfma_k<false><<<gemm_blocks, 256, 0, stream>>>(x, wt1, dinv, hbuf, N);
    agg_csr_k<false><<<agg_blocks, 256, 0, stream>>>(rowptr, csr_src, dinv, hbuf, b1, a1buf, N);

    // layer 2: h2' = (a1@W2)*dinv ; out = dinv*Agg(h2') + b2 (fp32)
    gemm_mfma_k<true><<<gemm_blocks, 256, 0, stream>>>(a1buf, wt2, dinv, hbuf, N);
    agg_csr_k<true><<<agg_blocks, 256, 0, stream>>>(rowptr, csr_src, dinv, hbuf, b2, out, N);
}